// Round 6
// baseline (3235.382 us; speedup 1.0000x reference)
//
#include <hip/hip_runtime.h>
#include <hip/hip_cooperative_groups.h>
#include <stdint.h>
#include <stddef.h>

namespace cg = cooperative_groups;

#define B_    64
#define T_    16
#define DF_   512
#define S_    196
#define DIN_  512
#define H_    8
#define DH_   64
#define DM_   1024
#define MEM_  25
#define HN_   32
#define MR_   (B_*S_)   /* 12544 rows per tick */

typedef short bf16x8 __attribute__((ext_vector_type(8)));
typedef float f32x4  __attribute__((ext_vector_type(4)));

__device__ __forceinline__ float b2f(short h){
  unsigned u = ((unsigned)(unsigned short)h) << 16;
  float f; __builtin_memcpy(&f, &u, 4); return f;
}
__device__ __forceinline__ short f2b(float f){
  unsigned u; __builtin_memcpy(&u, &f, 4);
  u = (u + 0x7fffu + ((u >> 16) & 1u)) >> 16;
  return (short)(unsigned short)u;
}
__device__ __forceinline__ float clip015(float d){
  return d < 0.f ? 0.f : (d > 15.f ? 15.f : d);
}

// ---------------------------------------------------------------------------
// bf16 MFMA GEMM, SINGLE-buffered (dbuf at 64KB LDS cut occupancy 44%->23%
// and regressed 460->605us in round 5 -- guide m132 lesson).
// C[M,N] = A[M,K]@W (+bias | +LN-fold epilogue), W passed as WT[N][K].
// 128x128 tile, BK=64, 4 waves 2x2, 16x16x32 MFMA, global_load_lds width-16,
// XOR chunk swizzle (T21).
// LNEPI: C[m][n] = iv[m]*(acc - mu[m]*gw[n]) + bw[n]  (LayerNorm folded).
// ---------------------------------------------------------------------------
template<int OUTF32, int LNEPI>
__global__ __launch_bounds__(256,2) void gemm_k(
    const short* __restrict__ A, const short* __restrict__ WT,
    void* __restrict__ Cout,
    const float* __restrict__ biasA, const float* __restrict__ biasB, int nsplit,
    const float* __restrict__ mu, const float* __restrict__ iv,
    const float* __restrict__ gw, const float* __restrict__ bw,
    int M, int N, int K, int lda, int ldc)
{
  __shared__ short lA[128*64];
  __shared__ short lB[128*64];
  const int tid = threadIdx.x;
  const int w = tid >> 6, l = tid & 63;
  const int m0 = blockIdx.x * 128, n0 = blockIdx.y * 128;
  const int wm = (w >> 1) * 64, wn = (w & 1) * 64;
  f32x4 acc[4][4];
  #pragma unroll
  for (int i=0;i<4;i++)
    #pragma unroll
    for (int j=0;j<4;j++) acc[i][j] = (f32x4){0.f,0.f,0.f,0.f};

  for (int k0 = 0; k0 < K; k0 += 64) {
    #pragma unroll
    for (int rnd = 0; rnd < 4; ++rnd) {
      int cb = (rnd*4 + w) * 64;
      int slot = cb + l;
      int row = slot >> 3, kb = slot & 7;
      int kc = k0 + ((kb ^ (row & 7)) << 3);
      int gm = m0 + row; if (gm > M-1) gm = M-1;
      __builtin_amdgcn_global_load_lds(
          (const __attribute__((address_space(1))) void*)(A + (size_t)gm * lda + kc),
          (__attribute__((address_space(3))) void*)&lA[cb*8], 16, 0, 0);
      __builtin_amdgcn_global_load_lds(
          (const __attribute__((address_space(1))) void*)(WT + (size_t)(n0 + row) * K + kc),
          (__attribute__((address_space(3))) void*)&lB[cb*8], 16, 0, 0);
    }
    asm volatile("s_waitcnt vmcnt(0)" ::: "memory");
    __syncthreads();
    #pragma unroll
    for (int ks = 0; ks < 2; ++ks) {
      bf16x8 af[4], bfr[4];
      #pragma unroll
      for (int i = 0; i < 4; ++i) {
        int ra = wm + i*16 + (l & 15);
        int c  = ks*4 + (l >> 4);
        af[i]  = *(const bf16x8*)&lA[ra*64 + ((c ^ (ra & 7)) << 3)];
        int rb = wn + i*16 + (l & 15);
        bfr[i] = *(const bf16x8*)&lB[rb*64 + ((c ^ (rb & 7)) << 3)];
      }
      #pragma unroll
      for (int i = 0; i < 4; ++i)
        #pragma unroll
        for (int j = 0; j < 4; ++j)
          acc[i][j] = __builtin_amdgcn_mfma_f32_16x16x32_bf16(af[i], bfr[j], acc[i][j], 0, 0, 0);
    }
    __syncthreads();
  }
  #pragma unroll
  for (int i = 0; i < 4; ++i) {
    #pragma unroll
    for (int j = 0; j < 4; ++j) {
      int gn = n0 + wn + j*16 + (l & 15);
      float gwn = 0.f, bwn = 0.f, bb = 0.f;
      if (LNEPI) { gwn = gw[gn]; bwn = bw[gn]; }
      else bb = biasA ? ((gn < nsplit) ? biasA[gn] : biasB[gn - nsplit]) : 0.f;
      #pragma unroll
      for (int r = 0; r < 4; ++r) {
        int gm = m0 + wm + i*16 + (l >> 4)*4 + r;
        if (gm < M) {
          float v;
          if (LNEPI) v = iv[gm]*(acc[i][j][r] - mu[gm]*gwn) + bwn;
          else       v = acc[i][j][r] + bb;
          if (OUTF32) ((float*)Cout)[(size_t)gm * ldc + gn] = v;
          else        ((short*)Cout)[(size_t)gm * ldc + gn] = f2b(v);
        }
      }
    }
  }
}

// ---------------------------------------------------------------------------
// Batched transpose of x over a tick chunk: f32 [B][T][DF][S] -> bf16 rows
// ((ti*B+b)*S + s) x [DF].
// ---------------------------------------------------------------------------
__global__ __launch_bounds__(256) void xpose_x(const float* __restrict__ x,
                                               short* __restrict__ xT, int t0, int tc)
{
  __shared__ float tile[32][33];
  int df0 = blockIdx.x*32, s0 = blockIdx.y*32;
  int z = blockIdx.z;
  int b = z / tc, ti = z % tc;
  int tx = threadIdx.x & 31, ty = threadIdx.x >> 5;
  const float* src = x + (size_t)(b*T_ + t0 + ti) * DF_ * S_;
  #pragma unroll
  for (int i = 0; i < 4; ++i) {
    int df = df0 + ty + i*8;
    int s  = s0 + tx;
    tile[ty+i*8][tx] = (s < S_) ? src[(size_t)df*S_ + s] : 0.f;
  }
  __syncthreads();
  short* dst = xT + (size_t)(ti*B_ + b) * S_ * DIN_;
  #pragma unroll
  for (int i = 0; i < 4; ++i) {
    int s  = s0 + ty + i*8;
    int df = df0 + tx;
    if (s < S_) dst[(size_t)s*DF_ + df] = f2b(tile[tx][ty+i*8]);
  }
}

// Weight transpose f32->bf16, optional per-row scale:
// out[c*ldo + coff + r] = in[r][c] * (scale ? scale[r] : 1)
__global__ __launch_bounds__(256) void wtrans(const float* __restrict__ in,
    short* __restrict__ out, int R, int C, int ldo, int coff,
    const float* __restrict__ scale)
{
  __shared__ float tile[32][33];
  int c0 = blockIdx.x*32, r0 = blockIdx.y*32;
  int tx = threadIdx.x & 31, ty = threadIdx.x >> 5;
  #pragma unroll
  for (int i = 0; i < 4; ++i) {
    int r = r0+ty+i*8;
    float sc = scale ? scale[r] : 1.f;
    tile[ty+i*8][tx] = in[(size_t)r*C + c0+tx] * sc;
  }
  __syncthreads();
  #pragma unroll
  for (int i = 0; i < 4; ++i)
    out[(size_t)(c0+ty+i*8)*ldo + coff + r0+tx] = f2b(tile[tx][ty+i*8]);
}

// f32 -> bf16 flat copy
__global__ __launch_bounds__(256) void cvtb(const float* __restrict__ in,
                                            short* __restrict__ out, int n)
{
  int i = blockIdx.x*256 + threadIdx.x;
  if (i < n) out[i] = f2b(in[i]);
}

// out[n] = (base?base[n]:0) + sum_k vec[k]*W[k*ldw+n]
__global__ __launch_bounds__(256) void bias_fold(const float* __restrict__ vec,
    const float* __restrict__ W, const float* __restrict__ base,
    float* __restrict__ out, int N, int ldw)
{
  int n = blockIdx.x*256 + threadIdx.x;
  if (n >= N) return;
  float a = base ? base[n] : 0.f;
  #pragma unroll 8
  for (int k = 0; k < 512; ++k) a += vec[k]*W[(size_t)k*ldw + n];
  out[n] = a;
}

// Row permutation of WsynF so GLU pairs land in the same MFMA fragment.
__global__ __launch_bounds__(256) void permrows(const short* __restrict__ in,
                                                short* __restrict__ out)
{
  int r = blockIdx.x;
  int k = r >> 4, i = r & 15;
  int src = (i < 8) ? (k*8 + i) : (1024 + k*8 + (i - 8));
  const bf16x8* s = (const bf16x8*)(in + (size_t)src*1536);
  bf16x8* d = (bf16x8*)(out + (size_t)r*1536);
  int j = threadIdx.x;
  if (j < 192) d[j] = s[j];
}

// Per-row LayerNorm stats over 512 bf16 cols: mu[r], iv[r]. One wave per row.
__global__ __launch_bounds__(256) void ln_stats(const short* __restrict__ in,
    float* __restrict__ mu, float* __restrict__ iv, int nrows)
{
  int w = threadIdx.x >> 6, l = threadIdx.x & 63;
  int r = blockIdx.x*4 + w;
  if (r >= nrows) return;
  bf16x8 v8 = *(const bf16x8*)&in[(size_t)r*512 + l*8];
  float s = 0.f, s2 = 0.f;
  #pragma unroll
  for (int j = 0; j < 8; ++j) { float v = b2f(v8[j]); s += v; s2 += v*v; }
  #pragma unroll
  for (int m = 1; m < 64; m <<= 1) { s += __shfl_xor(s, m, 64); s2 += __shfl_xor(s2, m, 64); }
  if (l == 0) {
    float mean = s * (1.f/512.f);
    float var  = s2 * (1.f/512.f) - mean*mean;
    mu[r] = mean;
    iv[r] = rsqrtf(var + 1e-5f);
  }
}

// ---------------------------------------------------------------------------
// outk body: 512 threads, one b. out-sync, pred, entropy for tick tt.
// ---------------------------------------------------------------------------
__device__ __forceinline__ void outk_body(int tt, int b, int tid,
    float* syncL, float* wred,
    const float* actT, float* ao, float* bo_s,
    const int* li_o, const int* ri_o, const float* decay_o,
    const float* Wout, const float* bout, float* out)
{
  int j = tid;
  float rr = expf(-clip015(decay_o[j]));
  float prod = actT[li_o[j]*64 + b] * actT[ri_o[j]*64 + b];
  float a2 = rr*ao[b*512+j] + prod; ao[b*512+j] = a2;
  float bb2 = rr*bo_s[b*512+j] + 1.f; bo_s[b*512+j] = bb2;
  syncL[j] = a2 * rsqrtf(bb2);
  __syncthreads();
  float a = bout[j];
  #pragma unroll 8
  for (int k = 0; k < 512; ++k) a += syncL[k]*Wout[k*512+j];
  out[((size_t)b*512 + j)*16 + tt] = a;
  int w = tid >> 6, l = tid & 63;
  float m = a;
  #pragma unroll
  for (int k = 32; k >= 1; k >>= 1) m = fmaxf(m, __shfl_xor(m, k, 64));
  if (l == 0) wred[w] = m;
  __syncthreads();
  float M = wred[0];
  #pragma unroll
  for (int k = 1; k < 8; ++k) M = fmaxf(M, wred[k]);
  float e = expf(a - M);
  float z = e, s1 = e*(a - M);
  #pragma unroll
  for (int k = 32; k >= 1; k >>= 1) { z += __shfl_xor(z, k, 64); s1 += __shfl_xor(s1, k, 64); }
  if (l == 0) { wred[8+w] = z; wred[16+w] = s1; }
  __syncthreads();
  if (tid == 0) {
    float Z = 0.f, S1 = 0.f;
    #pragma unroll
    for (int k = 0; k < 8; ++k) { Z += wred[8+k]; S1 += wred[16+k]; }
    float plp = S1 / Z - logf(Z);
    float ne = -plp * (1.f/logf(512.f));
    out[524288 + (size_t)b*32 + tt]      = ne;
    out[524288 + (size_t)b*32 + 16 + tt] = 1.f - ne;
  }
}

// ---------------------------------------------------------------------------
// fused_ticks (COOPERATIVE): all ticks of a chunk in one launch.
// 128 blocks x 512 threads. Per tick:
//   phase1: blocks 0-63 attn(t), blocks 64-127 outk(t-1)   -> grid.sync
//   phase2: synapse GEMM + GLU -> u                        -> grid.sync
//   phase3: LN(1024) -> hist slot + NLM -> actT, preb      -> grid.sync
// Final outk(T-1) after the loop when `last`.
// ---------------------------------------------------------------------------
__global__ __launch_bounds__(512) void fused_ticks(
    const short* __restrict__ KV, short* __restrict__ preb,
    const short* __restrict__ WsynP, const float* __restrict__ bsynF,
    float* __restrict__ u,
    const float* __restrict__ gsyn, const float* __restrict__ bln,
    float* __restrict__ hist,
    const float* __restrict__ W1, const float* __restrict__ b1,
    const float* __restrict__ W2, const float* __restrict__ b2,
    float* __restrict__ actT,
    const float* __restrict__ Wqq, const float* __restrict__ bqh,
    float* __restrict__ aa, float* __restrict__ ba,
    const int* __restrict__ li_a, const int* __restrict__ ri_a,
    const float* __restrict__ decay_a,
    float* __restrict__ ao, float* __restrict__ bo_s,
    const int* __restrict__ li_o, const int* __restrict__ ri_o,
    const float* __restrict__ decay_o,
    const float* __restrict__ Wout, const float* __restrict__ bout,
    float* __restrict__ out,
    int t0, int tcc, int last)
{
  cg::grid_group grid = cg::this_grid();
  __shared__ __attribute__((aligned(16))) float smem[3072];
  const int bid = blockIdx.x, tid = threadIdx.x;

  for (int ti = 0; ti < tcc; ++ti) {
    const int t = t0 + ti;
    // ---- phase 1: attn(t) || outk(t-1) ----
    if (bid < 64) {
      int b = bid;
      float* syncL = smem;
      float* qhL   = smem + 512;
      float* pL    = smem + 1024;   // 8*256
      int j = tid;
      float rr = expf(-clip015(decay_a[j]));
      float prod = actT[li_a[j]*64 + b] * actT[ri_a[j]*64 + b];
      float a2 = rr*aa[b*512+j] + prod; aa[b*512+j] = a2;
      float bb2 = rr*ba[b*512+j] + 1.f;  ba[b*512+j] = bb2;
      syncL[j] = a2 * rsqrtf(bb2);
      __syncthreads();
      float qa = bqh[j];
      #pragma unroll 8
      for (int k = 0; k < 512; ++k) qa += syncL[k]*Wqq[(size_t)k*512 + j];
      qhL[j] = qa;
      __syncthreads();
      int h = tid >> 6, l = tid & 63;
      const short* base = KV + (size_t)(ti*B_ + b) * S_ * 1024;
      float sc[4];
      #pragma unroll
      for (int r4 = 0; r4 < 4; ++r4) {
        int s = r4*64 + l;
        int sL = s < S_ ? s : S_-1;
        const short* kp = base + (size_t)sL*1024 + h*64;
        float a = 0.f;
        #pragma unroll
        for (int c = 0; c < 8; ++c) {
          bf16x8 kk = *(const bf16x8*)&kp[c*8];
          #pragma unroll
          for (int jj = 0; jj < 8; ++jj) a += qhL[h*64 + c*8 + jj] * b2f(kk[jj]);
        }
        sc[r4] = (s < S_) ? a * 0.125f : -1e30f;
      }
      float mx = fmaxf(fmaxf(sc[0], sc[1]), fmaxf(sc[2], sc[3]));
      #pragma unroll
      for (int k = 32; k >= 1; k >>= 1) mx = fmaxf(mx, __shfl_xor(mx, k, 64));
      float ps = 0.f;
      #pragma unroll
      for (int r4 = 0; r4 < 4; ++r4) {
        float p = expf(sc[r4] - mx);
        ps += p;
        pL[h*256 + r4*64 + l] = p;
      }
      #pragma unroll
      for (int k = 32; k >= 1; k >>= 1) ps += __shfl_xor(ps, k, 64);
      float inv = 1.f / ps;
      __syncthreads();
      // PV: 4 independent accumulators, deep unroll -> ~28 loads in flight
      const short* vb = base + 512 + h*64 + l;
      const float* pp = pL + h*256;
      float ac0=0.f, ac1=0.f, ac2=0.f, ac3=0.f;
      #pragma unroll 7
      for (int s4 = 0; s4 < 49; ++s4) {
        int s = s4*4;
        ac0 += pp[s]   * b2f(vb[(size_t)s*1024]);
        ac1 += pp[s+1] * b2f(vb[(size_t)(s+1)*1024]);
        ac2 += pp[s+2] * b2f(vb[(size_t)(s+2)*1024]);
        ac3 += pp[s+3] * b2f(vb[(size_t)(s+3)*1024]);
      }
      float accv = (ac0+ac1)+(ac2+ac3);
      preb[(size_t)b*1536 + h*64 + l] = f2b(accv * inv);
    } else if (t > 0) {
      outk_body(t-1, bid-64, tid, smem, smem+512, actT, ao, bo_s,
                li_o, ri_o, decay_o, Wout, bout, out);
    }
    grid.sync();
    // ---- phase 2: synapse GEMM + GLU -> u ----
    {
      int w = tid >> 6, l = tid & 63;
      int mf = w & 3, kh = w >> 2;
      int arow = mf*16 + (l & 15);
      int kbase = kh*768 + (l >> 4)*8;
      const short* ap = preb + (size_t)arow*1536 + kbase;
      const short* bp = WsynP + (size_t)(bid*16 + (l & 15))*1536 + kbase;
      f32x4 acc = (f32x4){0.f,0.f,0.f,0.f};
      #pragma unroll 4
      for (int ks = 0; ks < 24; ++ks) {
        bf16x8 av = *(const bf16x8*)(ap + ks*32);
        bf16x8 bv = *(const bf16x8*)(bp + ks*32);
        acc = __builtin_amdgcn_mfma_f32_16x16x32_bf16(av, bv, acc, 0, 0, 0);
      }
      f32x4* part = (f32x4*)smem;
      __syncthreads();
      part[w*64 + l] = acc;
      __syncthreads();
      if (w < 4) {
        f32x4 o1 = part[w*64 + l], o2 = part[(w+4)*64 + l];
        int c = l & 15;
        int colg = bid*8 + (c & 7);
        float bias = (c < 8) ? bsynF[colg] : bsynF[1024 + colg];
        float tv[4], pv[4];
        #pragma unroll
        for (int r2 = 0; r2 < 4; ++r2) tv[r2] = o1[r2] + o2[r2] + bias;
        #pragma unroll
        for (int r2 = 0; r2 < 4; ++r2) pv[r2] = __shfl_xor(tv[r2], 8, 64);
        if (c < 8) {
          #pragma unroll
          for (int r2 = 0; r2 < 4; ++r2) {
            float uu = tv[r2] * (1.f/(1.f + expf(-pv[r2])));
            int brow = w*16 + (l >> 4)*4 + r2;
            u[brow*1024 + colg] = uu;
          }
        }
      }
    }
    grid.sync();
    // ---- phase 3: LN(1024) -> hist slot + NLM ----
    {
      float* mst = smem;
      float* ist = smem + 64;
      {
        int b = tid >> 3, p = tid & 7;
        const float* up = u + b*1024 + p*128;
        float s = 0.f, s2 = 0.f;
        #pragma unroll 8
        for (int i = 0; i < 128; ++i) { float v = up[i]; s += v; s2 += v*v; }
        #pragma unroll
        for (int k = 4; k >= 1; k >>= 1) { s += __shfl_xor(s, k, 64); s2 += __shfl_xor(s2, k, 64); }
        if (p == 0) {
          float mean = s * (1.f/1024.f);
          float var  = s2 * (1.f/1024.f) - mean*mean;
          mst[b] = mean;
          ist[b] = rsqrtf(var + 1e-5f);
        }
      }
      __syncthreads();
      int n = (bid << 3) + (tid >> 6), b = tid & 63;
      float nv = (u[b*1024 + n] - mst[b]) * ist[b] * gsyn[n] + bln[n];
      int slot = t % MEM_;
      hist[((size_t)n*MEM_ + slot)*64 + b] = nv;
      float h[32];
      #pragma unroll
      for (int j = 0; j < 32; ++j) h[j] = b1[n*32+j];
      #pragma unroll 5
      for (int m = 0; m < MEM_; ++m) {
        int phys = (t + 1 + m) % MEM_;
        float hv = (m == MEM_-1) ? nv : hist[((size_t)n*MEM_ + phys)*64 + b];
        const float* wp = &W1[((size_t)n*MEM_ + m)*32];
        #pragma unroll
        for (int j = 0; j < 32; ++j) h[j] += hv * wp[j];
      }
      float acc = b2[n];
      #pragma unroll
      for (int j = 0; j < 32; ++j) acc += fmaxf(h[j], 0.f) * W2[n*32+j];
      actT[n*64 + b] = acc;
      preb[(size_t)b*1536 + 512 + n] = f2b(acc);
    }
    grid.sync();
  }
  if (last && bid >= 64) {
    __syncthreads();
    outk_body(t0+tcc-1, bid-64, tid, smem, smem+512, actT, ao, bo_s,
              li_o, ri_o, decay_o, Wout, bout, out);
  }
}

// Re-initialize all recurrent state (graph-replay deterministic).
__global__ __launch_bounds__(256) void initk(float* __restrict__ aa, float* __restrict__ ba,
    float* __restrict__ ao, float* __restrict__ bo_s,
    float* __restrict__ actT, float* __restrict__ hist, short* __restrict__ preb,
    const float* __restrict__ init_act, const float* __restrict__ init_hist,
    const int* __restrict__ li_o, const int* __restrict__ ri_o)
{
  int i = blockIdx.x*256 + threadIdx.x;
  if (i < 64*512) {
    aa[i] = 0.f; ba[i] = 0.f;
    int j = i & 511;
    ao[i] = init_act[li_o[j]] * init_act[ri_o[j]];
    bo_s[i] = 1.f;
  }
  if (i < 65536) {
    int n = i >> 6, b = i & 63;
    actT[i] = init_act[n];
    preb[(size_t)b*1536 + 512 + n] = f2b(init_act[n]);
  }
  if (i < DM_*MEM_*64) {
    int nm = i >> 6;
    hist[i] = init_hist[nm];
  }
}

// ---------------------------------------------------------------------------
extern "C" void kernel_launch(void* const* d_in, const int* in_sizes, int n_in,
                              void* d_out, int out_size, void* d_ws, size_t ws_size,
                              hipStream_t stream)
{
  (void)in_sizes; (void)n_in; (void)out_size;
  const float* x       = (const float*)d_in[0];
  const float* Wqp     = (const float*)d_in[1];
  const float* bqp     = (const float*)d_in[2];
  const float* Wkv     = (const float*)d_in[3];
  const float* bkv     = (const float*)d_in[4];
  const float* g_kv    = (const float*)d_in[5];
  const float* b_kv    = (const float*)d_in[6];
  const float* Wq      = (const float*)d_in[7];
  const float* bq      = (const float*)d_in[8];
  const float* Wk      = (const float*)d_in[9];
  const float* bk      = (const float*)d_in[10];
  const float* Wv      = (const float*)d_in[11];
  const float* bv      = (const float*)d_in[12];
  const float* Wo      = (const float*)d_in[13];
  const float* bo_p    = (const float*)d_in[14];
  const float* Wsyn    = (const float*)d_in[15];
  const float* bsyn    = (const float*)d_in[16];
  const float* g_syn   = (const float*)d_in[17];
  const float* b_syn   = (const float*)d_in[18];
  const float* W1      = (const float*)d_in[19];
  const float* b1      = (const float*)d_in[20];
  const float* W2      = (const float*)d_in[21];
  const float* b2      = (const float*)d_in[22];
  const float* init_act  = (const float*)d_in[23];
  const float* init_hist = (const float*)d_in[24];
  const float* decay_a = (const float*)d_in[25];
  const float* decay_o = (const float*)d_in[26];
  const float* Wout    = (const float*)d_in[27];
  const float* bout    = (const float*)d_in[28];
  const int* li_a = (const int*)d_in[29];
  const int* ri_a = (const int*)d_in[30];
  const int* li_o = (const int*)d_in[31];
  const int* ri_o = (const int*)d_in[32];

  char* ws = (char*)d_ws;
  size_t off = 0;
  auto alloc = [&](size_t bytes) { char* p = ws + off; off += (bytes + 255) & ~(size_t)255; return p; };
  short* WkvT   = (short*)alloc(512*512*2);
  short* WkkvT  = (short*)alloc(1024*512*2);     // g-scaled rows of [Wk|Wv]^T
  short* WsynF  = (short*)alloc(2048*1536*2);
  short* WsynP  = (short*)alloc(2048*1536*2);
  short* WsynTt = (short*)alloc(2048*512*2);
  short* WqpB   = (short*)alloc(512*512*2);
  short* WqT    = (short*)alloc(512*512*2);
  short* WoB    = (short*)alloc(512*512*2);
  float* Wqq    = (float*)alloc(512*512*4);
  float* bqh    = (float*)alloc(512*4);
  float* bsynF  = (float*)alloc(2048*4);
  float* gw     = (float*)alloc(1024*4);
  float* bw     = (float*)alloc(1024*4);
  short* preb   = (short*)alloc(64*1536*2);
  float* u      = (float*)alloc(64*1024*4);
  float* aa     = (float*)alloc(64*512*4);
  float* ba     = (float*)alloc(64*512*4);
  float* ao     = (float*)alloc(64*512*4);
  float* bo_s   = (float*)alloc(64*512*4);
  float* actT   = (float*)alloc(1024*64*4);
  float* hist   = (float*)alloc((size_t)1024*25*64*4);
  float* mu     = (float*)alloc((size_t)MR_*T_*4);
  float* iv     = (float*)alloc((size_t)MR_*T_*4);
  size_t fixed_end = off;

  const size_t PT_XT = (size_t)MR_*512*2;
  const size_t PT_KV = (size_t)MR_*1024*2;
  const size_t per_tick = PT_XT*2 + PT_KV;   // xT + kvp + KV
  size_t avail = (ws_size > fixed_end) ? ws_size - fixed_end : 0;
  int tc = (int)(avail / per_tick);
  if (tc > T_) tc = T_;
  if (tc < 1) tc = 1;

  short* xT  = (short*)(ws + fixed_end);
  short* kvp = (short*)((char*)xT  + PT_XT*tc);
  short* KV  = (short*)((char*)kvp + PT_XT*tc);

  const int BIG = 1 << 30;
  const float* FN = nullptr;

  initk<<<6400, 256, 0, stream>>>(aa, ba, ao, bo_s, actT, hist, preb,
                                  init_act, init_hist, li_o, ri_o);
  wtrans<<<dim3(16,16), 256, 0, stream>>>(Wkv, WkvT, 512, 512, 512, 0, nullptr);
  wtrans<<<dim3(16,16), 256, 0, stream>>>(Wk,  WkkvT, 512, 512, 512, 0, g_kv);
  wtrans<<<dim3(16,16), 256, 0, stream>>>(Wv,  WkkvT + (size_t)512*512, 512, 512, 512, 0, g_kv);
  wtrans<<<dim3(64,32), 256, 0, stream>>>(Wsyn + (size_t)512*2048, WsynF, 1024, 2048, 1536, 512, nullptr);
  wtrans<<<dim3(64,16), 256, 0, stream>>>(Wsyn, WsynTt, 512, 2048, 512, 0, nullptr);
  wtrans<<<dim3(16,16), 256, 0, stream>>>(Wq,  WqT, 512, 512, 512, 0, nullptr);
  cvtb<<<1024, 256, 0, stream>>>(Wqp, WqpB, 512*512);
  cvtb<<<1024, 256, 0, stream>>>(Wo,  WoB,  512*512);
  gemm_k<1,0><<<dim3(4,4), 256, 0, stream>>>(WqpB, WqT, Wqq, nullptr, nullptr, BIG,
                                             FN, FN, FN, FN, 512, 512, 512, 512, 512);
  gemm_k<0,0><<<dim3(16,4), 256, 0, stream>>>(WsynTt, WoB, WsynF, nullptr, nullptr, BIG,
                                              FN, FN, FN, FN, 2048, 512, 512, 512, 1536);
  permrows<<<2048, 256, 0, stream>>>(WsynF, WsynP);
  bias_fold<<<2, 256, 0, stream>>>(bqp,  Wq,   bq,   bqh,   512,  512);
  bias_fold<<<8, 256, 0, stream>>>(bo_p, Wsyn, bsyn, bsynF, 2048, 2048);
  bias_fold<<<2, 256, 0, stream>>>(g_kv, Wk, nullptr, gw,       512, 512);
  bias_fold<<<2, 256, 0, stream>>>(g_kv, Wv, nullptr, gw + 512, 512, 512);
  bias_fold<<<2, 256, 0, stream>>>(b_kv, Wk, bk, bw,       512, 512);
  bias_fold<<<2, 256, 0, stream>>>(b_kv, Wv, bv, bw + 512, 512, 512);

  for (int t0 = 0; t0 < T_; t0 += tc) {
    int tcc = (t0 + tc <= T_) ? tc : (T_ - t0);
    int Mc = MR_ * tcc;
    xpose_x<<<dim3(16,7,B_*tcc), 256, 0, stream>>>(x, xT, t0, tcc);
    gemm_k<0,0><<<dim3(98*tcc,4), 256, 0, stream>>>(xT, WkvT, kvp, bkv, bkv, BIG,
                                                    FN, FN, FN, FN, Mc, 512, 512, 512, 512);
    ln_stats<<<(Mc+3)/4, 256, 0, stream>>>(kvp, mu, iv, Mc);
    gemm_k<0,1><<<dim3(98*tcc,8), 256, 0, stream>>>(kvp, WkkvT, KV, nullptr, nullptr, BIG,
                                                    mu, iv, gw, bw, Mc, 1024, 512, 512, 1024);
    {
      int t0v = t0, tccv = tcc;
      int last = (t0 + tcc == T_) ? 1 : 0;
      float* outp = (float*)d_out;
      void* kp[] = { (void*)&KV, (void*)&preb, (void*)&WsynP, (void*)&bsynF, (void*)&u,
                     (void*)&g_syn, (void*)&b_syn, (void*)&hist,
                     (void*)&W1, (void*)&b1, (void*)&W2, (void*)&b2,
                     (void*)&actT, (void*)&Wqq, (void*)&bqh,
                     (void*)&aa, (void*)&ba, (void*)&li_a, (void*)&ri_a, (void*)&decay_a,
                     (void*)&ao, (void*)&bo_s, (void*)&li_o, (void*)&ri_o, (void*)&decay_o,
                     (void*)&Wout, (void*)&bout, (void*)&outp,
                     (void*)&t0v, (void*)&tccv, (void*)&last };
      hipLaunchCooperativeKernel((void*)fused_ticks, dim3(128), dim3(512), kp, 0, stream);
    }
  }
}